// Round 13
// baseline (110.817 us; speedup 1.0000x reference)
//
#include <hip/hip_runtime.h>
#include <stdint.h>

typedef _Float16 f16x8 __attribute__((ext_vector_type(8)));
typedef float f32x16 __attribute__((ext_vector_type(16)));
typedef unsigned int u32x4 __attribute__((ext_vector_type(4)));

#define T_OBS 50
#define PRED 12

// ws layout (f16 elements):
//   encA [T<4][kt<9][lane<64][j<8] = 18432   (kt 0..7 = W_hh K-tiles, kt 8 = [Wih|bias] x-tile)
//   decA same, +18432
//   fcA  [kt<8][lane<64][j<8] = 4096
#define DEC_OFF 18432
#define FC_OFF  36864
#define WS_ELEMS 40960

// Baked unit permutation: swap bits 2<->3 of the k-label (verified R3/R5,
// absmax 0.0156).
__device__ __forceinline__ int swap23(int k) {
  return (k & ~12) | ((k & 4) << 1) | ((k & 8) >> 1);
}

// RNN weights pre-scaled by 2*log2(e): MFMA accumulator is directly the exp2
// argument for tanh(v) = 1 - 2/(1+exp2(2*log2e*v)). fc NOT scaled.
// R9-R12 forensics: those failures were a mis-transcribed exchange tail
// (pw==1 frag placement inverted), NOT this fold and NOT s_sleep. This kernel
// uses R5's exchange VERBATIM (own frags always Bl[0..3], partner via pw^1).
#define ARG_SCALE 2.8853900817779268f

__global__ void prep_kernel(const float* __restrict__ Wih_e, const float* __restrict__ Whh_e,
                            const float* __restrict__ bih_e, const float* __restrict__ bhh_e,
                            const float* __restrict__ Wih_d, const float* __restrict__ Whh_d,
                            const float* __restrict__ bih_d, const float* __restrict__ bhh_d,
                            const float* __restrict__ fcW,
                            unsigned short* __restrict__ ws) {
  int idx = blockIdx.x * 256 + threadIdx.x;
  if (idx >= WS_ELEMS) return;
  float val = 0.0f;
  const int j = idx & 7;
  const int lane = (idx >> 3) & 63;
  const int hi = lane >> 5;
  const int mlo = lane & 31;
  if (idx < FC_OFF) {
    const bool enc = idx < DEC_OFF;
    const int e = enc ? idx : idx - DEC_OFF;
    const int rem = e >> 9;          // T*9 + kt
    const int kt = rem % 9;
    const int T = rem / 9;
    const int m = 32 * T + mlo;      // physical output unit (A-row = lane&31)
    const float* Wih = enc ? Wih_e : Wih_d;
    const float* Whh = enc ? Whh_e : Whh_d;
    const float* bih = enc ? bih_e : bih_d;
    const float* bhh = enc ? bhh_e : bhh_d;
    if (kt < 8) {
      const int kap = 16 * kt + 8 * hi + j;
      val = Whh[m * 128 + swap23(kap)] * ARG_SCALE;
    } else {
      const int c = 8 * hi + j;      // x-tile: x0,x1,x2,bias at c=0..3, rest 0
      if (c < 3) val = Wih[m * 3 + c] * ARG_SCALE;
      else if (c == 3) val = (bih[m] + bhh[m]) * ARG_SCALE;
    }
  } else {
    const int e = idx - FC_OFF;
    const int kt = e >> 9;           // 0..7
    const int kap = 16 * kt + 8 * hi + j;
    if (mlo < 3) val = fcW[mlo * 128 + swap23(kap)];   // rows 3..31 zero, UNSCALED
  }
  _Float16 h = (_Float16)val;
  ws[idx] = __builtin_bit_cast(unsigned short, h);
}

__device__ __forceinline__ unsigned int pk2(float a, float b) {
  return __builtin_bit_cast(unsigned int, __builtin_amdgcn_cvt_pkrtz(a, b));
}

__device__ __forceinline__ f16x8 ldfrag(const unsigned short* p) {
  return __builtin_bit_cast(f16x8, *(const u32x4*)p);
}

// tanh for 4 values sharing ONE v_rcp (exact leave-one-out algebra).
// Inputs pre-scaled: a = 2*log2e*v. Clamp at 30: 4-way product < 2^120
// (finite), tanh(30/2.885)==1 to f32 anyway; exp2(-big)->0 -> t=-1, fine.
__device__ __forceinline__ void tanh4(float a0, float a1, float a2, float a3,
                                      float& t0, float& t1, float& t2, float& t3) {
  a0 = fminf(a0, 30.f); a1 = fminf(a1, 30.f);
  a2 = fminf(a2, 30.f); a3 = fminf(a3, 30.f);
  const float e0 = __builtin_amdgcn_exp2f(a0);
  const float e1 = __builtin_amdgcn_exp2f(a1);
  const float e2 = __builtin_amdgcn_exp2f(a2);
  const float e3 = __builtin_amdgcn_exp2f(a3);
  const float d0 = 1.f + e0, d1 = 1.f + e1, d2 = 1.f + e2, d3 = 1.f + e3;
  const float p01 = d0 * d1, p23 = d2 * d3;
  const float r = __builtin_amdgcn_rcpf(p01 * p23);
  const float r01 = r * p23, r23 = r * p01;
  t0 = __builtin_fmaf(-2.f, r01 * d1, 1.f);   // r01*d1 = 1/d0
  t1 = __builtin_fmaf(-2.f, r01 * d0, 1.f);
  t2 = __builtin_fmaf(-2.f, r23 * d3, 1.f);
  t3 = __builtin_fmaf(-2.f, r23 * d2, 1.f);
}

// Block = 4 waves = 2 independent PAIRS; each pair covers 32 seqs with
// M-split-2 (wave owns 2 m-tiles = 64 units -> produces 4 k-frags, trades 4
// with its partner). 512 blocks x 4 waves = 2048 waves = exactly 2/SIMD,
// SINGLE batch. Fragment positions use kt=(4*pw+i)&7 so own frags sit at
// i=0..3 (for BOTH waves) and all register indices are compile-time.
__global__ __launch_bounds__(256, 2) void traj_kernel(
    const float* __restrict__ src, const unsigned short* __restrict__ ws,
    const float* __restrict__ fcb, float* __restrict__ out) {
  __shared__ unsigned short xch[2][2][2][4][64][8];  // [par][pair][pw][frag][lane][j] = 32KB

  const int lane = (int)(threadIdx.x & 63u);
  const int w = (int)(threadIdx.x >> 6u);            // 0..3
  const int pw = w & 1;                              // wave-in-pair
  const int pr = w >> 1;                             // pair id
  const int seq = blockIdx.x * 64 + pr * 32 + (lane & 31);
  const int b = seq >> 6;                            // /64 agents
  const int a = seq & 63;

  // ---- A-frags for my two m-tiles (mt = 2pw, 2pw+1): h-part at kt=(4pw+i)&7 ----
  f16x8 Ah[2][8], Ax[2];
  #pragma unroll
  for (int t = 0; t < 2; ++t) {
    const int mt = 2 * pw + t;
    #pragma unroll
    for (int i = 0; i < 8; ++i) {
      const int kt = (4 * pw + i) & 7;
      Ah[t][i] = ldfrag(ws + (size_t)((mt * 9 + kt) * 64 + lane) * 8);
    }
    Ax[t] = ldfrag(ws + (size_t)((mt * 9 + 8) * 64 + lane) * 8);
  }

  const float* xq = src + (size_t)b * (T_OBS * 192) + a * 3;
  float x0 = xq[0], x1 = xq[1], x2 = xq[2];
  xq += 192;

  f16x8 Bl[8];
  #pragma unroll
  for (int i = 0; i < 8; ++i) {
    u32x4 zz = (u32x4)0u;
    Bl[i] = __builtin_bit_cast(f16x8, zz);           // h0 = 0
  }

  // xf: only k-slots 0..3 on hi=0 lanes matter (A zero elsewhere; keep rest 0)
  u32x4 xfu = (u32x4)0u;
  xfu[0] = pk2(x0, x1);
  xfu[1] = pk2(x2, 1.0f);

  auto rnn_step = [&](int par) {
    const f32x16 z = (f32x16)0.0f;
    f16x8 xf = __builtin_bit_cast(f16x8, xfu);
    // x/bias tile first: independent of exchanged h -> overlaps barrier/ds_read
    f32x16 a0 = __builtin_amdgcn_mfma_f32_32x32x16_f16(Ax[0], xf, z, 0, 0, 0);
    f32x16 a1 = __builtin_amdgcn_mfma_f32_32x32x16_f16(Ax[1], xf, z, 0, 0, 0);
    #pragma unroll
    for (int i = 0; i < 8; ++i) {
      a0 = __builtin_amdgcn_mfma_f32_32x32x16_f16(Ah[0][i], Bl[i], a0, 0, 0, 0);
      a1 = __builtin_amdgcn_mfma_f32_32x32x16_f16(Ah[1][i], Bl[i], a1, 0, 0, 0);
    }
    // tanh (shared-rcp groups of 4) + pack into B-frag layout (lane-local)
    float t[16], u[16];
    tanh4(a0[0],  a0[1],  a0[2],  a0[3],  t[0],  t[1],  t[2],  t[3]);
    tanh4(a0[4],  a0[5],  a0[6],  a0[7],  t[4],  t[5],  t[6],  t[7]);
    tanh4(a0[8],  a0[9],  a0[10], a0[11], t[8],  t[9],  t[10], t[11]);
    tanh4(a0[12], a0[13], a0[14], a0[15], t[12], t[13], t[14], t[15]);
    tanh4(a1[0],  a1[1],  a1[2],  a1[3],  u[0],  u[1],  u[2],  u[3]);
    tanh4(a1[4],  a1[5],  a1[6],  a1[7],  u[4],  u[5],  u[6],  u[7]);
    tanh4(a1[8],  a1[9],  a1[10], a1[11], u[8],  u[9],  u[10], u[11]);
    tanh4(a1[12], a1[13], a1[14], a1[15], u[12], u[13], u[14], u[15]);
    u32x4 F0, F1, F2, F3;
    #pragma unroll
    for (int q = 0; q < 4; ++q) {
      F0[q] = pk2(t[2 * q],     t[2 * q + 1]);
      F1[q] = pk2(t[8 + 2 * q], t[8 + 2 * q + 1]);
      F2[q] = pk2(u[2 * q],     u[2 * q + 1]);
      F3[q] = pk2(u[8 + 2 * q], u[8 + 2 * q + 1]);
    }
    *(u32x4*)&xch[par][pr][pw][0][lane][0] = F0;
    *(u32x4*)&xch[par][pr][pw][1][lane][0] = F1;
    *(u32x4*)&xch[par][pr][pw][2][lane][0] = F2;
    *(u32x4*)&xch[par][pr][pw][3][lane][0] = F3;
    __syncthreads();
    Bl[0] = __builtin_bit_cast(f16x8, F0);           // own frags: i=0..3 (BOTH waves)
    Bl[1] = __builtin_bit_cast(f16x8, F1);
    Bl[2] = __builtin_bit_cast(f16x8, F2);
    Bl[3] = __builtin_bit_cast(f16x8, F3);
    Bl[4] = ldfrag(&xch[par][pr][pw ^ 1][0][lane][0]);  // partner frags: i=4..7
    Bl[5] = ldfrag(&xch[par][pr][pw ^ 1][1][lane][0]);
    Bl[6] = ldfrag(&xch[par][pr][pw ^ 1][2][lane][0]);
    Bl[7] = ldfrag(&xch[par][pr][pw ^ 1][3][lane][0]);
  };

  // ---- encoder: steps 0..48 with distance-1 x prefetch, step 49 peeled ----
  for (int s = 0; s < T_OBS - 1; ++s) {
    const float nx0 = xq[0], nx1 = xq[1], nx2 = xq[2];
    xq += 192;
    rnn_step(s & 1);
    xfu[0] = pk2(nx0, nx1);
    xfu[1] = pk2(nx2, 1.0f);
  }
  rnn_step(1);                      // s=49; xfu keeps x[49] = decoder input 0

  // ---- decoder weights (same kt rotation) + fc frags ----
  #pragma unroll
  for (int t = 0; t < 2; ++t) {
    const int mt = 2 * pw + t;
    #pragma unroll
    for (int i = 0; i < 8; ++i) {
      const int kt = (4 * pw + i) & 7;
      Ah[t][i] = ldfrag(ws + DEC_OFF + (size_t)((mt * 9 + kt) * 64 + lane) * 8);
    }
    Ax[t] = ldfrag(ws + DEC_OFF + (size_t)((mt * 9 + 8) * 64 + lane) * 8);
  }
  f16x8 Afc[8];
  #pragma unroll
  for (int i = 0; i < 8; ++i) {
    const int kt = (4 * pw + i) & 7;
    Afc[i] = ldfrag(ws + FC_OFF + (size_t)(kt * 64 + lane) * 8);
  }
  const float fb0 = fcb[0], fb1 = fcb[1], fb2 = fcb[2];

  float* op = out + (size_t)b * (PRED * 192) + a * 3;

  // ---- decoder: 12 autoregressive steps ----
  for (int p = 0; p < PRED; ++p) {
    rnn_step(p & 1);
    // fc head on updated h (both waves of the pair compute; pw==0 stores)
    const f32x16 z = (f32x16)0.0f;
    f32x16 pf = __builtin_amdgcn_mfma_f32_32x32x16_f16(Afc[0], Bl[0], z, 0, 0, 0);
    #pragma unroll
    for (int i = 1; i < 8; ++i)
      pf = __builtin_amdgcn_mfma_f32_32x32x16_f16(Afc[i], Bl[i], pf, 0, 0, 0);
    const float p0 = pf[0] + fb0;   // fc rows 0..2 -> regs 0..2 on hi=0 lanes
    const float p1 = pf[1] + fb1;
    const float p2 = pf[2] + fb2;
    if (pw == 0 && lane < 32) {
      op[p * 192 + 0] = p0;
      op[p * 192 + 1] = p1;
      op[p * 192 + 2] = p2;
    }
    // autoregressive feedback (hi=1 lanes hold finite junk that hits A's zeros)
    xfu[0] = pk2(p0, p1);
    xfu[1] = pk2(p2, 1.0f);
  }
}

extern "C" void kernel_launch(void* const* d_in, const int* in_sizes, int n_in,
                              void* d_out, int out_size, void* d_ws, size_t ws_size,
                              hipStream_t stream) {
  const float* src   = (const float*)d_in[0];
  const float* Wih_e = (const float*)d_in[1];
  const float* Whh_e = (const float*)d_in[2];
  const float* bih_e = (const float*)d_in[3];
  const float* bhh_e = (const float*)d_in[4];
  const float* Wih_d = (const float*)d_in[5];
  const float* Whh_d = (const float*)d_in[6];
  const float* bih_d = (const float*)d_in[7];
  const float* bhh_d = (const float*)d_in[8];
  const float* fcW   = (const float*)d_in[9];
  const float* fcb   = (const float*)d_in[10];
  (void)in_sizes; (void)n_in; (void)out_size; (void)ws_size;

  unsigned short* ws = (unsigned short*)d_ws;

  prep_kernel<<<(WS_ELEMS + 255) / 256, 256, 0, stream>>>(
      Wih_e, Whh_e, bih_e, bhh_e, Wih_d, Whh_d, bih_d, bhh_d, fcW, ws);

  // 32768 seqs / 64 per block (2 pairs x 32 seqs, M-split-2) = 512 blocks
  traj_kernel<<<512, 256, 0, stream>>>(src, ws, fcb, (float*)d_out);
}